// Round 10
// baseline (403.096 us; speedup 1.0000x reference)
//
#include <hip/hip_runtime.h>
#include <hip/hip_bf16.h>
#include <stdint.h>

// Problem constants (KANLayer): B=8192, I=256, O=256, NUM_BASIS=7, ORDER=3
#define B_SZ 8192
#define I_SZ 256
#define O_SZ 256
#define KDIM 2048  // I_SZ * 8  (7 basis + 1 silu per input feature)
#define BM 32      // rows per block
#define BN 128     // output cols per block
#define KT 64      // K per tile = 8 features
#define NT 32      // KDIM / KT
#define NPART 128  // min/max partial rows

typedef __bf16 bf16x8 __attribute__((ext_vector_type(8)));
typedef float f32x4 __attribute__((ext_vector_type(4)));

// Kernel 1: per-column min/max partials (proven r7 shape).
__global__ __launch_bounds__(256) void minmax_partial(
    const float* __restrict__ x, float* __restrict__ pmin,
    float* __restrict__ pmax) {
  const int cg = threadIdx.x & 63;
  const int rs = threadIdx.x >> 6;
  const int r0 = blockIdx.x * 64;
  const float* p = x + (size_t)(r0 + rs) * I_SZ + cg * 4;
  float4 mn = {1e30f, 1e30f, 1e30f, 1e30f};
  float4 mx = {-1e30f, -1e30f, -1e30f, -1e30f};
#pragma unroll
  for (int k = 0; k < 16; ++k) {
    const float4 v = *reinterpret_cast<const float4*>(p + (size_t)k * 4 * I_SZ);
    mn.x = fminf(mn.x, v.x); mn.y = fminf(mn.y, v.y);
    mn.z = fminf(mn.z, v.z); mn.w = fminf(mn.w, v.w);
    mx.x = fmaxf(mx.x, v.x); mx.y = fmaxf(mx.y, v.y);
    mx.z = fmaxf(mx.z, v.z); mx.w = fmaxf(mx.w, v.w);
  }
  __shared__ float rmn[4][I_SZ], rmx[4][I_SZ];
  *reinterpret_cast<float4*>(&rmn[rs][cg * 4]) = mn;
  *reinterpret_cast<float4*>(&rmx[rs][cg * 4]) = mx;
  __syncthreads();
  if (threadIdx.x < 64) {
    float4 a, b;
    const int c0 = threadIdx.x * 4;
    a.x = fminf(fminf(rmn[0][c0+0], rmn[1][c0+0]), fminf(rmn[2][c0+0], rmn[3][c0+0]));
    a.y = fminf(fminf(rmn[0][c0+1], rmn[1][c0+1]), fminf(rmn[2][c0+1], rmn[3][c0+1]));
    a.z = fminf(fminf(rmn[0][c0+2], rmn[1][c0+2]), fminf(rmn[2][c0+2], rmn[3][c0+2]));
    a.w = fminf(fminf(rmn[0][c0+3], rmn[1][c0+3]), fminf(rmn[2][c0+3], rmn[3][c0+3]));
    b.x = fmaxf(fmaxf(rmx[0][c0+0], rmx[1][c0+0]), fmaxf(rmx[2][c0+0], rmx[3][c0+0]));
    b.y = fmaxf(fmaxf(rmx[0][c0+1], rmx[1][c0+1]), fmaxf(rmx[2][c0+1], rmx[3][c0+1]));
    b.z = fmaxf(fmaxf(rmx[0][c0+2], rmx[1][c0+2]), fmaxf(rmx[2][c0+2], rmx[3][c0+2]));
    b.w = fmaxf(fmaxf(rmx[0][c0+3], rmx[1][c0+3]), fmaxf(rmx[2][c0+3], rmx[3][c0+3]));
    *reinterpret_cast<float4*>(&pmin[blockIdx.x * I_SZ + c0]) = a;
    *reinterpret_cast<float4*>(&pmax[blockIdx.x * I_SZ + c0]) = b;
  }
}

// Kernel 2: pack weights -> Wp[o, i*8+m] bf16, pre-swizzled (unit ^= o&7).
__global__ void pack_W(const float* __restrict__ bw,
                       const float* __restrict__ sw,
                       const float* __restrict__ coeff,
                       __hip_bfloat16* __restrict__ W) {
  const int idx = blockIdx.x * blockDim.x + threadIdx.x;
  const int i = idx & (I_SZ - 1);
  const int o = idx >> 8;
  const float s = sw[idx];
  union { __hip_bfloat16 h[8]; float4 f4; } u;
#pragma unroll
  for (int m = 0; m < 7; ++m)
    u.h[m] = __float2bfloat16(coeff[(size_t)idx * 7 + m] * s);
  u.h[7] = __float2bfloat16(bw[idx]);
  const size_t off = (size_t)o * KDIM + (size_t)((i ^ (o & 7)) << 3);
  *reinterpret_cast<float4*>(&W[off]) = u.f4;
}

__device__ __forceinline__ void async16(const __hip_bfloat16* g, __hip_bfloat16* l) {
  __builtin_amdgcn_global_load_lds(
      (const __attribute__((address_space(1))) void*)g,
      (__attribute__((address_space(3))) void*)l, 16, 0, 0);
}

__device__ __forceinline__ uint32_t bfc(float f) {
  union { __hip_bfloat16 b; unsigned short s; } c;
  c.b = __float2bfloat16(f);
  return (uint32_t)c.s;
}

// Kernel 3 (templated): fused basis+GEMM. R=2 (A shared via LDS within block),
// cheap shift-based eval, B triple-buffered staged 2 tiles ahead, counted
// vmcnt(5) + one raw s_barrier per K-step. REPEAT>1 loops the K-loop for
// ablation timing; DO_EVAL/DO_STAGE stub phases (sinks keep loads live).
template <int REPEAT, bool DO_EVAL, bool DO_STAGE>
__global__ __launch_bounds__(256, 2) void gk(
    const float* __restrict__ x, const __hip_bfloat16* __restrict__ W,
    const float* __restrict__ pmin, const float* __restrict__ pmax,
    const float* __restrict__ bias, float* __restrict__ out) {
  __shared__ __align__(16) __hip_bfloat16 Blds[3][BN * KT];  // 3 x 16KB
  __shared__ __align__(16) __hip_bfloat16 Alds[2][BM * KT];  // 2 x 4KB
  __shared__ float2 scl[I_SZ];                                // 2KB

  const int t = threadIdx.x;
  const int lane = t & 63;
  const int wave = t >> 6;            // 0..3 -> n-offset 32*wave
  const int fr = lane & 15, fk = lane >> 4;

  const int bid = blockIdx.x;
  const int swz = (bid & 7) * 64 + (bid >> 3);
  const int bm = swz >> 1, bnb = swz & 1;
  const int r0 = bm * BM, c0 = bnb * BN;

  const int arow = t >> 3, af_ = t & 7;
  const float* xq = x + (size_t)(r0 + arow) * I_SZ + af_;
  const __hip_bfloat16* gb = W + (size_t)(c0 + (t >> 3)) * KDIM + (t & 7) * 8;
  const int aoff = arow * KT + ((af_ ^ (arow & 7)) << 3);

  auto stageB = [&](int buf, int tile) {
    if constexpr (DO_STAGE) {
      const __hip_bfloat16* g = gb + tile * KT;
      async16(g,                      &Blds[buf][t * 8]);
      async16(g + (size_t)32 * KDIM,  &Blds[buf][2048 + t * 8]);
      async16(g + (size_t)64 * KDIM,  &Blds[buf][4096 + t * 8]);
      async16(g + (size_t)96 * KDIM,  &Blds[buf][6144 + t * 8]);
    }
  };

  // closed-form uniform cubic B-spline (== reference's truncated de Boor),
  // packed via 128-bit shift: slots ci-3..ci get q0..q3, slot 7 = silu.
  auto evalA = [&](int abuf, int tile, float xv) {
    uint4 val;
    if constexpr (DO_EVAL) {
      const float2 s2 = scl[tile * 8 + af_];
      const float xn = __builtin_fmaf(xv, s2.x, s2.y);   // ~[-1,1]
      const float sp = __builtin_fmaf(xn, 5.0f, 5.0f);   // ~[0,10]
      const float c6 = fminf(fmaxf(floorf(sp), 0.0f), 6.0f);
      const int ci = (int)c6;
      const float u = sp - c6;
      const float zm = (sp > 7.0f) ? 0.0f : (1.0f / 6.0f);
      const float u2 = u * u, u3 = u2 * u, t1 = 1.0f - u;
      const float q3 = u3 * zm;
      const float q0 = (t1 * t1) * (t1 * zm);
      float h2 = __builtin_fmaf(-3.0f, u, 3.0f);
      h2 = __builtin_fmaf(h2, u, 3.0f);
      h2 = __builtin_fmaf(h2, u, 1.0f);                   // -3u^3+3u^2+3u+1
      float h1 = __builtin_fmaf(3.0f, u, -6.0f);
      h1 = __builtin_fmaf(h1, u2, 4.0f);                  // 3u^3-6u^2+4
      const float q2v = h2 * zm, q1v = h1 * zm;
      const float silu = xn * __builtin_amdgcn_rcpf(1.0f + __expf(-xn));
      const uint64_t D = (uint64_t)(bfc(q0) | (bfc(q1v) << 16)) |
                         ((uint64_t)(bfc(q2v) | (bfc(q3) << 16)) << 32);
      const int tt = ci * 16 - 48;                        // [-48, 48]
      const uint64_t ls = D << (tt & 63);
      const uint64_t rs = D >> ((-tt) & 63);
      uint64_t lo = (tt >= 0) ? ls : rs;
      uint64_t hi = (tt >= 0) ? ((D >> ((63 - tt) & 63)) >> 1) : 0ull;
      hi = (hi & 0x0000FFFFFFFFFFFFull) | ((uint64_t)bfc(silu) << 48);
      val = make_uint4((uint32_t)lo, (uint32_t)(lo >> 32),
                       (uint32_t)hi, (uint32_t)(hi >> 32));
    } else {
      asm volatile("" :: "v"(xv));  // keep x-load live (vmcnt semantics)
      val = make_uint4(0x3f803f80u, 0x3f803f80u, 0x3f803f80u, 0x3f803f80u);
    }
    *reinterpret_cast<uint4*>(&Alds[abuf][aoff]) = val;
  };

  f32x4 acc[2][2] = {{{0.f,0.f,0.f,0.f},{0.f,0.f,0.f,0.f}},
                     {{0.f,0.f,0.f,0.f},{0.f,0.f,0.f,0.f}}};

  auto compute = [&](int bbuf, int abuf) {
    bf16x8 af[2][2], bg[2][2];
#pragma unroll
    for (int m = 0; m < 2; ++m)
#pragma unroll
      for (int kk = 0; kk < 2; ++kk) {
        const int row = m * 16 + fr;
        const int unit = ((kk << 2) | fk) ^ (row & 7);
        af[m][kk] = *reinterpret_cast<const bf16x8*>(&Alds[abuf][row * KT + unit * 8]);
      }
#pragma unroll
    for (int n = 0; n < 2; ++n)
#pragma unroll
      for (int kk = 0; kk < 2; ++kk) {
        const int row = wave * 32 + n * 16 + fr;
        const int unit = ((kk << 2) | fk) ^ (row & 7);
        bg[n][kk] = *reinterpret_cast<const bf16x8*>(&Blds[bbuf][row * KT + unit * 8]);
      }
#pragma unroll
    for (int kk = 0; kk < 2; ++kk)
#pragma unroll
      for (int m = 0; m < 2; ++m)
#pragma unroll
        for (int n = 0; n < 2; ++n)
          acc[m][n] = __builtin_amdgcn_mfma_f32_16x16x32_bf16(
              af[m][kk], bg[n][kk], acc[m][n], 0, 0, 0);
  };

  // prologue: issue stages + x loads first; scl reduce overlaps their latency.
  stageB(0, 0);
  stageB(1, 1);
  float xv_c = xq[0];
  float xv_n = xq[8];
  {
    float mn = 1e30f, mx = -1e30f;
#pragma unroll 8
    for (int p = 0; p < NPART; ++p) {
      mn = fminf(mn, pmin[p * I_SZ + t]);
      mx = fmaxf(mx, pmax[p * I_SZ + t]);
    }
    const float w = fmaxf(mx - mn, 0.01f);
    const float rhw = 2.0f / w;
    scl[t] = make_float2(rhw, -0.5f * (mx + mn) * rhw);
  }
  __syncthreads();          // scl visible + stage(0,1) + x drained (prologue)
  evalA(0, 0, xv_c);
  xv_c = xv_n;
  asm volatile("s_waitcnt lgkmcnt(0)" ::: "memory");
  __builtin_amdgcn_s_barrier();

  constexpr int NTT = NT * REPEAT;
  int bcur = 0;
  for (int kt = 0; kt < NTT; ++kt) {
    const int bn2 = (bcur + 2 > 2) ? bcur - 1 : bcur + 2;  // (bcur+2)%3
    if (kt + 2 < NTT) {
      stageB(bn2, (kt + 2) & (NT - 1));      // 4 vmem (2 tiles ahead)
      xv_n = xq[((kt + 2) & (NT - 1)) * 8];  // 1 vmem
    }
    if (kt + 1 < NTT) evalA((kt + 1) & 1, (kt + 1) & (NT - 1), xv_c);
    compute(bcur, kt & 1);
    if (kt < NTT - 1) {
      if (kt + 2 < NTT)
        asm volatile("s_waitcnt vmcnt(5) lgkmcnt(0)" ::: "memory");
      else
        asm volatile("s_waitcnt vmcnt(0) lgkmcnt(0)" ::: "memory");
      __builtin_amdgcn_s_barrier();
      xv_c = xv_n;
    }
    bcur = (bcur == 2) ? 0 : bcur + 1;
  }

  // epilogue: C/D layout col=lane&15, row=(lane>>4)*4+reg  [m89/m91]
#pragma unroll
  for (int m = 0; m < 2; ++m)
#pragma unroll
    for (int n = 0; n < 2; ++n) {
      const int col = c0 + wave * 32 + n * 16 + fr;
      const float bc = bias[col];
#pragma unroll
      for (int r = 0; r < 4; ++r) {
        const int row = r0 + m * 16 + fk * 4 + r;
        out[(size_t)row * O_SZ + col] = acc[m][n][r] + bc;
      }
    }
}

extern "C" void kernel_launch(void* const* d_in, const int* in_sizes, int n_in,
                              void* d_out, int out_size, void* d_ws, size_t ws_size,
                              hipStream_t stream) {
  const float* x     = (const float*)d_in[0];
  const float* bw    = (const float*)d_in[1];
  const float* sw    = (const float*)d_in[2];
  const float* coeff = (const float*)d_in[3];
  const float* bias  = (const float*)d_in[4];
  float* out = (float*)d_out;

  char* ws = (char*)d_ws;
  __hip_bfloat16* Wbuf = (__hip_bfloat16*)ws;                    // 1 MiB
  float* pmin = (float*)(ws + (size_t)O_SZ * KDIM * 2);          // 128 KiB
  float* pmax = pmin + NPART * I_SZ;                             // 128 KiB
  float* diag = (float*)(ws + (size_t)16 * 1024 * 1024);         // 8 MiB scratch

  const int grid = (B_SZ / BM) * (O_SZ / BN);  // 512

  minmax_partial<<<NPART, 256, 0, stream>>>(x, pmin, pmax);
  pack_W<<<(O_SZ * I_SZ) / 256, 256, 0, stream>>>(bw, sw, coeff, Wbuf);

  // --- ablation variants (write scratch; REPEAT=6 to surface in top-5) ---
  gk<6, true,  true ><<<grid, 256, 0, stream>>>(x, Wbuf, pmin, pmax, bias, diag);
  gk<6, false, true ><<<grid, 256, 0, stream>>>(x, Wbuf, pmin, pmax, bias, diag);
  gk<6, true,  false><<<grid, 256, 0, stream>>>(x, Wbuf, pmin, pmax, bias, diag);
  gk<6, false, false><<<grid, 256, 0, stream>>>(x, Wbuf, pmin, pmax, bias, diag);

  // --- real kernel ---
  gk<1, true, true><<<grid, 256, 0, stream>>>(x, Wbuf, pmin, pmax, bias, out);
}

// Round 11
// 48.863 us; speedup vs baseline: 8.2496x; 8.2496x over previous
//
#include <hip/hip_runtime.h>
#include <hip/hip_bf16.h>
#include <stdint.h>

// Problem constants (KANLayer): B=8192, I=256, O=256, NUM_BASIS=7, ORDER=3
#define B_SZ 8192
#define I_SZ 256
#define O_SZ 256
#define KDIM 2048   // I_SZ * 8  (7 basis + 1 silu per input feature)
#define BMB 128     // rows per block (4 waves x 32)
#define BNB 64      // output cols per block
#define FT 16       // features per K-tile (K = 128)
#define NTILE 16    // KDIM / 128
#define NPART 128   // min/max partial rows

typedef __bf16 bf16x8 __attribute__((ext_vector_type(8)));
typedef float f32x4 __attribute__((ext_vector_type(4)));

// Kernel 1: per-column min/max partials (proven r7 shape).
__global__ __launch_bounds__(256) void minmax_partial(
    const float* __restrict__ x, float* __restrict__ pmin,
    float* __restrict__ pmax) {
  const int cg = threadIdx.x & 63;
  const int rs = threadIdx.x >> 6;
  const int r0 = blockIdx.x * 64;
  const float* p = x + (size_t)(r0 + rs) * I_SZ + cg * 4;
  float4 mn = {1e30f, 1e30f, 1e30f, 1e30f};
  float4 mx = {-1e30f, -1e30f, -1e30f, -1e30f};
#pragma unroll
  for (int k = 0; k < 16; ++k) {
    const float4 v = *reinterpret_cast<const float4*>(p + (size_t)k * 4 * I_SZ);
    mn.x = fminf(mn.x, v.x); mn.y = fminf(mn.y, v.y);
    mn.z = fminf(mn.z, v.z); mn.w = fminf(mn.w, v.w);
    mx.x = fmaxf(mx.x, v.x); mx.y = fmaxf(mx.y, v.y);
    mx.z = fmaxf(mx.z, v.z); mx.w = fmaxf(mx.w, v.w);
  }
  __shared__ float rmn[4][I_SZ], rmx[4][I_SZ];
  *reinterpret_cast<float4*>(&rmn[rs][cg * 4]) = mn;
  *reinterpret_cast<float4*>(&rmx[rs][cg * 4]) = mx;
  __syncthreads();
  if (threadIdx.x < 64) {
    float4 a, b;
    const int c0 = threadIdx.x * 4;
    a.x = fminf(fminf(rmn[0][c0+0], rmn[1][c0+0]), fminf(rmn[2][c0+0], rmn[3][c0+0]));
    a.y = fminf(fminf(rmn[0][c0+1], rmn[1][c0+1]), fminf(rmn[2][c0+1], rmn[3][c0+1]));
    a.z = fminf(fminf(rmn[0][c0+2], rmn[1][c0+2]), fminf(rmn[2][c0+2], rmn[3][c0+2]));
    a.w = fminf(fminf(rmn[0][c0+3], rmn[1][c0+3]), fminf(rmn[2][c0+3], rmn[3][c0+3]));
    b.x = fmaxf(fmaxf(rmx[0][c0+0], rmx[1][c0+0]), fmaxf(rmx[2][c0+0], rmx[3][c0+0]));
    b.y = fmaxf(fmaxf(rmx[0][c0+1], rmx[1][c0+1]), fmaxf(rmx[2][c0+1], rmx[3][c0+1]));
    b.z = fmaxf(fmaxf(rmx[0][c0+2], rmx[1][c0+2]), fmaxf(rmx[2][c0+2], rmx[3][c0+2]));
    b.w = fmaxf(fmaxf(rmx[0][c0+3], rmx[1][c0+3]), fmaxf(rmx[2][c0+3], rmx[3][c0+3]));
    *reinterpret_cast<float4*>(&pmin[blockIdx.x * I_SZ + c0]) = a;
    *reinterpret_cast<float4*>(&pmax[blockIdx.x * I_SZ + c0]) = b;
  }
}

// Kernel 2: pack weights -> Wp[o, i*8+m] bf16, pre-swizzled (unit ^= o&7);
// block 0 additionally reduces min/max partials into (rhw, -centre*rhw).
__global__ void pack_W(const float* __restrict__ bw,
                       const float* __restrict__ sw,
                       const float* __restrict__ coeff,
                       __hip_bfloat16* __restrict__ W,
                       const float* __restrict__ pmin,
                       const float* __restrict__ pmax,
                       float* __restrict__ cenrhw) {
  const int idx = blockIdx.x * blockDim.x + threadIdx.x;
  const int i = idx & (I_SZ - 1);
  const int o = idx >> 8;
  const float s = sw[idx];
  union { __hip_bfloat16 h[8]; float4 f4; } u;
#pragma unroll
  for (int m = 0; m < 7; ++m)
    u.h[m] = __float2bfloat16(coeff[(size_t)idx * 7 + m] * s);
  u.h[7] = __float2bfloat16(bw[idx]);
  const size_t off = (size_t)o * KDIM + (size_t)((i ^ (o & 7)) << 3);
  *reinterpret_cast<float4*>(&W[off]) = u.f4;

  if (blockIdx.x == 0) {
    const int c = threadIdx.x;
    float mn = 1e30f, mx = -1e30f;
#pragma unroll 8
    for (int p = 0; p < NPART; ++p) {
      mn = fminf(mn, pmin[p * I_SZ + c]);
      mx = fmaxf(mx, pmax[p * I_SZ + c]);
    }
    const float width = fmaxf(mx - mn, 0.01f);
    const float rhw = 2.0f / width;
    cenrhw[2 * c]     = rhw;
    cenrhw[2 * c + 1] = -0.5f * (mx + mn) * rhw;
  }
}

__device__ __forceinline__ void async16(const __hip_bfloat16* g, __hip_bfloat16* l) {
  __builtin_amdgcn_global_load_lds(
      (const __attribute__((address_space(1))) void*)g,
      (__attribute__((address_space(3))) void*)l, 16, 0, 0);
}

__device__ __forceinline__ uint32_t bfc(float f) {
  union { __hip_bfloat16 b; unsigned short s; } c;
  c.b = __float2bfloat16(f);
  return (uint32_t)c.s;
}

// closed-form uniform cubic B-spline (== reference's truncated de Boor),
// packed into the 8-bf16 A-fragment via 128-bit funnel shift (r10, verified).
__device__ __forceinline__ bf16x8 evalOne(float xv, float2 s2) {
  const float xn = __builtin_fmaf(xv, s2.x, s2.y);
  const float sp = __builtin_fmaf(xn, 5.0f, 5.0f);
  const float c6 = fminf(fmaxf(floorf(sp), 0.0f), 6.0f);
  const int ci = (int)c6;
  const float u = sp - c6;
  const float zm = (sp > 7.0f) ? 0.0f : (1.0f / 6.0f);
  const float u2 = u * u, u3 = u2 * u, t1 = 1.0f - u;
  const float q3 = u3 * zm;
  const float q0 = (t1 * t1) * (t1 * zm);
  float h2 = __builtin_fmaf(-3.0f, u, 3.0f);
  h2 = __builtin_fmaf(h2, u, 3.0f);
  h2 = __builtin_fmaf(h2, u, 1.0f);                 // -3u^3+3u^2+3u+1
  float h1 = __builtin_fmaf(3.0f, u, -6.0f);
  h1 = __builtin_fmaf(h1, u2, 4.0f);                // 3u^3-6u^2+4
  const float q2v = h2 * zm, q1v = h1 * zm;
  const float silu = xn * __builtin_amdgcn_rcpf(1.0f + __expf(-xn));
  const uint64_t D = (uint64_t)(bfc(q0) | (bfc(q1v) << 16)) |
                     ((uint64_t)(bfc(q2v) | (bfc(q3) << 16)) << 32);
  const int tt = ci * 16 - 48;                      // [-48, 48]
  const uint64_t ls = D << (tt & 63);
  const uint64_t rs = D >> ((-tt) & 63);
  uint64_t lo = (tt >= 0) ? ls : rs;
  uint64_t hi = (tt >= 0) ? ((D >> ((63 - tt) & 63)) >> 1) : 0ull;
  hi = (hi & 0x0000FFFFFFFFFFFFull) | ((uint64_t)bfc(silu) << 48);
  union { uint32_t w[4]; bf16x8 v; } r;
  r.w[0] = (uint32_t)lo; r.w[1] = (uint32_t)(lo >> 32);
  r.w[2] = (uint32_t)hi; r.w[3] = (uint32_t)(hi >> 32);
  return r.v;
}

// Kernel 3: fused basis+GEMM. A in REGISTERS (M-split waves: zero in-block
// redundancy; R = O/BNB = 4 across blocks). B-only LDS, double-buffered,
// KT=128 (16 iters), counted vmcnt(8) + one s_barrier per iter. No in-loop
// ds_write -> no lgkm producer edge across waves.
__global__ __launch_bounds__(256) void gemm_fused(
    const float* __restrict__ x, const __hip_bfloat16* __restrict__ W,
    const float* __restrict__ cenrhw, const float* __restrict__ bias,
    float* __restrict__ out) {
  __shared__ __align__(16) __hip_bfloat16 Blds[2][BNB * FT * 8];  // 2 x 16KB
  __shared__ float2 scl[I_SZ];                                     // 2KB

  const int t = threadIdx.x;
  const int lane = t & 63;
  const int wave = t >> 6;            // 0..3 -> row-offset 32*wave
  const int fr = lane & 15, fk = lane >> 4;

  // XCD swizzle, bn-minor: the 4 col-panels of one row-group land on one XCD
  // -> W panels + x row-slice L2-resident.
  const int bid = blockIdx.x;
  const int swz = (bid & 7) * 32 + (bid >> 3);   // grid 256
  const int bm = swz >> 2, bn = swz & 3;
  const int r0 = bm * BMB, c0 = bn * BNB;

  scl[t] = reinterpret_cast<const float2*>(cenrhw)[t];

  // B staging: thread t covers LDS 16B-units p = t + 256q (q=0..3);
  // row = p>>4 (0..63), useg = p&15. Source pre-swizzled at pack time.
  const __hip_bfloat16* gb = W + (size_t)(c0 + (t >> 4)) * KDIM + (t & 15) * 8;

  auto stageB = [&](int buf, int kt) {
    const __hip_bfloat16* g = gb + kt * 128;
#pragma unroll
    for (int q = 0; q < 4; ++q)
      async16(g + (size_t)16 * q * KDIM, &Blds[buf][(t + 256 * q) * 8]);
  };

  // x: lane evaluates rows (r0 + wave*32 + fr) and (+16), features
  // kt*16 + 4s + fk, s = 0..3.
  const float* xq = x + (size_t)(r0 + wave * 32 + fr) * I_SZ + fk;

  f32x4 acc[2][4] = {{{0,0,0,0},{0,0,0,0},{0,0,0,0},{0,0,0,0}},
                     {{0,0,0,0},{0,0,0,0},{0,0,0,0},{0,0,0,0}}};

  // prologue: stage tile 0, load x tile 0
  stageB(0, 0);
  float xv0[4], xv1[4], xn0[4], xn1[4];
#pragma unroll
  for (int s = 0; s < 4; ++s) {
    xv0[s] = xq[4 * s];
    xv1[s] = xq[16 * I_SZ + 4 * s];
  }
  __syncthreads();   // scl visible + stage(0) drained

  for (int kt = 0; kt < NTILE; ++kt) {
    const int buf = kt & 1;
    if (kt + 1 < NTILE) {
      stageB(buf ^ 1, kt + 1);              // 4 vmem
      const int o = (kt + 1) * 16;
#pragma unroll
      for (int s = 0; s < 4; ++s) {         // 8 vmem
        xn0[s] = xq[o + 4 * s];
        xn1[s] = xq[16 * I_SZ + o + 4 * s];
      }
    }
    // evals (VALU, overlaps MFMA/LDS below via scheduler)
    bf16x8 af0[4], af1[4];
#pragma unroll
    for (int s = 0; s < 4; ++s) {
      const float2 s2 = scl[kt * 16 + 4 * s + fk];
      af0[s] = evalOne(xv0[s], s2);
      af1[s] = evalOne(xv1[s], s2);
    }
    const __hip_bfloat16* L = Blds[buf];
#pragma unroll
    for (int s = 0; s < 4; ++s) {
      bf16x8 bg[4];
#pragma unroll
      for (int n = 0; n < 4; ++n) {
        const int row = n * 16 + fr;
        const int unit = (4 * s + fk) ^ (row & 7);   // XOR low3; bit3 kept
        bg[n] = *reinterpret_cast<const bf16x8*>(&L[row * 128 + unit * 8]);
      }
#pragma unroll
      for (int n = 0; n < 4; ++n) {
        acc[0][n] = __builtin_amdgcn_mfma_f32_16x16x32_bf16(af0[s], bg[n], acc[0][n], 0, 0, 0);
        acc[1][n] = __builtin_amdgcn_mfma_f32_16x16x32_bf16(af1[s], bg[n], acc[1][n], 0, 0, 0);
      }
    }
    if (kt + 1 < NTILE) {
      // stage(kt+1) done (8 newer x-loads may fly); x regs tracked by compiler
      asm volatile("s_waitcnt vmcnt(8)" ::: "memory");
      __builtin_amdgcn_s_barrier();
#pragma unroll
      for (int s = 0; s < 4; ++s) { xv0[s] = xn0[s]; xv1[s] = xn1[s]; }
    }
  }

  // epilogue: C/D layout col=lane&15, row=(lane>>4)*4+reg  [m89/m91]
#pragma unroll
  for (int m = 0; m < 2; ++m)
#pragma unroll
    for (int n = 0; n < 4; ++n) {
      const int col = c0 + n * 16 + fr;
      const float bc = bias[col];
#pragma unroll
      for (int r = 0; r < 4; ++r) {
        const int row = r0 + wave * 32 + m * 16 + fk * 4 + r;
        out[(size_t)row * O_SZ + col] = acc[m][n][r] + bc;
      }
    }
}

extern "C" void kernel_launch(void* const* d_in, const int* in_sizes, int n_in,
                              void* d_out, int out_size, void* d_ws, size_t ws_size,
                              hipStream_t stream) {
  const float* x     = (const float*)d_in[0];
  const float* bw    = (const float*)d_in[1];
  const float* sw    = (const float*)d_in[2];
  const float* coeff = (const float*)d_in[3];
  const float* bias  = (const float*)d_in[4];
  float* out = (float*)d_out;

  char* ws = (char*)d_ws;
  __hip_bfloat16* Wbuf = (__hip_bfloat16*)ws;                    // 1 MiB
  float* pmin   = (float*)(ws + (size_t)O_SZ * KDIM * 2);        // 128 KiB
  float* pmax   = pmin + NPART * I_SZ;                           // 128 KiB
  float* cenrhw = pmax + NPART * I_SZ;                           // 2 KiB

  minmax_partial<<<NPART, 256, 0, stream>>>(x, pmin, pmax);
  pack_W<<<(O_SZ * I_SZ) / 256, 256, 0, stream>>>(bw, sw, coeff, Wbuf,
                                                  pmin, pmax, cenrhw);
  gemm_fused<<<(B_SZ / BMB) * (O_SZ / BNB), 256, 0, stream>>>(x, Wbuf, cenrhw,
                                                              bias, out);
}

// Round 12
// 44.524 us; speedup vs baseline: 9.0535x; 1.0975x over previous
//
#include <hip/hip_runtime.h>
#include <hip/hip_bf16.h>
#include <stdint.h>

// Problem constants (KANLayer): B=8192, I=256, O=256, NUM_BASIS=7, ORDER=3
#define B_SZ 8192
#define I_SZ 256
#define O_SZ 256
#define KDIM 2048   // I_SZ * 8  (7 basis + 1 silu per input feature)
#define BMB 128     // rows per block (4 waves x 32, M-split)
#define BNB 64      // output cols per block
#define NPART 128   // min/max partial rows

typedef __bf16 bf16x8 __attribute__((ext_vector_type(8)));
typedef float f32x4 __attribute__((ext_vector_type(4)));

// Kernel 1: per-column min/max partials (proven r7 shape).
__global__ __launch_bounds__(256) void minmax_partial(
    const float* __restrict__ x, float* __restrict__ pmin,
    float* __restrict__ pmax) {
  const int cg = threadIdx.x & 63;
  const int rs = threadIdx.x >> 6;
  const int r0 = blockIdx.x * 64;
  const float* p = x + (size_t)(r0 + rs) * I_SZ + cg * 4;
  float4 mn = {1e30f, 1e30f, 1e30f, 1e30f};
  float4 mx = {-1e30f, -1e30f, -1e30f, -1e30f};
#pragma unroll
  for (int k = 0; k < 16; ++k) {
    const float4 v = *reinterpret_cast<const float4*>(p + (size_t)k * 4 * I_SZ);
    mn.x = fminf(mn.x, v.x); mn.y = fminf(mn.y, v.y);
    mn.z = fminf(mn.z, v.z); mn.w = fminf(mn.w, v.w);
    mx.x = fmaxf(mx.x, v.x); mx.y = fmaxf(mx.y, v.y);
    mx.z = fmaxf(mx.z, v.z); mx.w = fmaxf(mx.w, v.w);
  }
  __shared__ float rmn[4][I_SZ], rmx[4][I_SZ];
  *reinterpret_cast<float4*>(&rmn[rs][cg * 4]) = mn;
  *reinterpret_cast<float4*>(&rmx[rs][cg * 4]) = mx;
  __syncthreads();
  if (threadIdx.x < 64) {
    float4 a, b;
    const int c0 = threadIdx.x * 4;
    a.x = fminf(fminf(rmn[0][c0+0], rmn[1][c0+0]), fminf(rmn[2][c0+0], rmn[3][c0+0]));
    a.y = fminf(fminf(rmn[0][c0+1], rmn[1][c0+1]), fminf(rmn[2][c0+1], rmn[3][c0+1]));
    a.z = fminf(fminf(rmn[0][c0+2], rmn[1][c0+2]), fminf(rmn[2][c0+2], rmn[3][c0+2]));
    a.w = fminf(fminf(rmn[0][c0+3], rmn[1][c0+3]), fminf(rmn[2][c0+3], rmn[3][c0+3]));
    b.x = fmaxf(fmaxf(rmx[0][c0+0], rmx[1][c0+0]), fmaxf(rmx[2][c0+0], rmx[3][c0+0]));
    b.y = fmaxf(fmaxf(rmx[0][c0+1], rmx[1][c0+1]), fmaxf(rmx[2][c0+1], rmx[3][c0+1]));
    b.z = fmaxf(fmaxf(rmx[0][c0+2], rmx[1][c0+2]), fmaxf(rmx[2][c0+2], rmx[3][c0+2]));
    b.w = fmaxf(fmaxf(rmx[0][c0+3], rmx[1][c0+3]), fmaxf(rmx[2][c0+3], rmx[3][c0+3]));
    *reinterpret_cast<float4*>(&pmin[blockIdx.x * I_SZ + c0]) = a;
    *reinterpret_cast<float4*>(&pmax[blockIdx.x * I_SZ + c0]) = b;
  }
}

// Kernel 2: pack weights -> Wp[o, i*8+m] bf16, pre-swizzled (chunk ^= o&7);
// block 0 additionally reduces min/max partials into (rhw, -centre*rhw).
__global__ void pack_W(const float* __restrict__ bw,
                       const float* __restrict__ sw,
                       const float* __restrict__ coeff,
                       __hip_bfloat16* __restrict__ W,
                       const float* __restrict__ pmin,
                       const float* __restrict__ pmax,
                       float* __restrict__ cenrhw) {
  const int idx = blockIdx.x * blockDim.x + threadIdx.x;
  const int i = idx & (I_SZ - 1);
  const int o = idx >> 8;
  const float s = sw[idx];
  union { __hip_bfloat16 h[8]; float4 f4; } u;
#pragma unroll
  for (int m = 0; m < 7; ++m)
    u.h[m] = __float2bfloat16(coeff[(size_t)idx * 7 + m] * s);
  u.h[7] = __float2bfloat16(bw[idx]);
  const size_t off = (size_t)o * KDIM + (size_t)((i ^ (o & 7)) << 3);
  *reinterpret_cast<float4*>(&W[off]) = u.f4;

  if (blockIdx.x == 0) {
    const int c = threadIdx.x;
    float mn = 1e30f, mx = -1e30f;
#pragma unroll 8
    for (int p = 0; p < NPART; ++p) {
      mn = fminf(mn, pmin[p * I_SZ + c]);
      mx = fmaxf(mx, pmax[p * I_SZ + c]);
    }
    const float width = fmaxf(mx - mn, 0.01f);
    const float rhw = 2.0f / width;
    cenrhw[2 * c]     = rhw;
    cenrhw[2 * c + 1] = -0.5f * (mx + mn) * rhw;
  }
}

__device__ __forceinline__ void async16(const __hip_bfloat16* g, __hip_bfloat16* l) {
  __builtin_amdgcn_global_load_lds(
      (const __attribute__((address_space(1))) void*)g,
      (__attribute__((address_space(3))) void*)l, 16, 0, 0);
}

__device__ __forceinline__ uint32_t bfc(float f) {
  union { __hip_bfloat16 b; unsigned short s; } c;
  c.b = __float2bfloat16(f);
  return (uint32_t)c.s;
}

// closed-form uniform cubic B-spline (== reference's truncated de Boor),
// packed into the 8-bf16 A-fragment via 128-bit funnel shift (verified r10/r11).
__device__ __forceinline__ bf16x8 evalOne(float xv, float2 s2) {
  const float xn = __builtin_fmaf(xv, s2.x, s2.y);
  const float sp = __builtin_fmaf(xn, 5.0f, 5.0f);
  const float c6 = fminf(fmaxf(floorf(sp), 0.0f), 6.0f);
  const int ci = (int)c6;
  const float u = sp - c6;
  const float zm = (sp > 7.0f) ? 0.0f : (1.0f / 6.0f);
  const float u2 = u * u, u3 = u2 * u, t1 = 1.0f - u;
  const float q3 = u3 * zm;
  const float q0 = (t1 * t1) * (t1 * zm);
  float h2 = __builtin_fmaf(-3.0f, u, 3.0f);
  h2 = __builtin_fmaf(h2, u, 3.0f);
  h2 = __builtin_fmaf(h2, u, 1.0f);                 // -3u^3+3u^2+3u+1
  float h1 = __builtin_fmaf(3.0f, u, -6.0f);
  h1 = __builtin_fmaf(h1, u2, 4.0f);                // 3u^3-6u^2+4
  const float q2v = h2 * zm, q1v = h1 * zm;
  const float silu = xn * __builtin_amdgcn_rcpf(1.0f + __expf(-xn));
  const uint64_t D = (uint64_t)(bfc(q0) | (bfc(q1v) << 16)) |
                     ((uint64_t)(bfc(q2v) | (bfc(q3) << 16)) << 32);
  const int tt = ci * 16 - 48;                      // [-48, 48]
  const uint64_t ls = D << (tt & 63);
  const uint64_t rs = D >> ((-tt) & 63);
  uint64_t lo = (tt >= 0) ? ls : rs;
  uint64_t hi = (tt >= 0) ? ((D >> ((63 - tt) & 63)) >> 1) : 0ull;
  hi = (hi & 0x0000FFFFFFFFFFFFull) | ((uint64_t)bfc(silu) << 48);
  union { uint32_t w[4]; bf16x8 v; } r;
  r.w[0] = (uint32_t)lo; r.w[1] = (uint32_t)(lo >> 32);
  r.w[2] = (uint32_t)hi; r.w[3] = (uint32_t)(hi >> 32);
  return r.v;
}

// Kernel 3: fused basis+GEMM with W RESIDENT IN LDS — zero in-loop barriers.
// Block = 128 rows x 64 cols (grid 256 = 1 block/CU, no tail). W half-panel
// (64 cols x K=1024 = 128KB) staged once per half via global_load_lds; K-loop
// is {x loads -> in-register eval -> read-only ds_read_b128 -> MFMA} with no
// sync. Only 2 barriers total (around the half-K reload). A in registers,
// M-split waves (zero in-block eval redundancy; R=4 across blocks).
__global__ __launch_bounds__(256) void gemm_fused(
    const float* __restrict__ x, const __hip_bfloat16* __restrict__ W,
    const float* __restrict__ cenrhw, const float* __restrict__ bias,
    float* __restrict__ out) {
  __shared__ __align__(16) __hip_bfloat16 Wlds[BNB][1024];  // 128KB
  __shared__ float2 scl[I_SZ];                               // 2KB

  const int t = threadIdx.x;
  const int lane = t & 63;
  const int wave = t >> 6;            // 0..3 -> row-offset 32*wave
  const int fr = lane & 15, fk = lane >> 4;

  // XCD swizzle, bn-minor: 4 col-panels of one row-group share an XCD
  // -> x row-slice L2-local; W (1MB) L2-resident anyway.
  const int bid = blockIdx.x;
  const int swz = (bid & 7) * 32 + (bid >> 3);   // grid 256
  const int bm = swz >> 2, bn = swz & 3;
  const int r0 = bm * BMB, c0 = bn * BNB;

  scl[t] = reinterpret_cast<const float2*>(cenrhw)[t];

  // W staging: LDS 16B-unit p = t + 256q (q=0..31): row o' = p>>7 =
  // (t>>7)+2q, chunk c' = p&127 = t&127. Source pre-swizzled at pack time.
  const __hip_bfloat16* gw = W + (size_t)(c0 + (t >> 7)) * KDIM + (t & 127) * 8;
  auto stageW = [&](int h) {
    const __hip_bfloat16* g = gw + h * 1024;
    __hip_bfloat16* l = &Wlds[0][0] + (size_t)t * 8;
#pragma unroll
    for (int q = 0; q < 32; ++q)
      async16(g + (size_t)2 * q * KDIM, l + (size_t)2048 * q);
  };

  // x: lane evaluates rows (r0 + wave*32 + fr) and (+16); feature for
  // global k-step s (0..63) is 4s+fk.
  const float* xq = x + (size_t)(r0 + wave * 32 + fr) * I_SZ + fk;

  f32x4 acc[2][4] = {{{0,0,0,0},{0,0,0,0},{0,0,0,0},{0,0,0,0}},
                     {{0,0,0,0},{0,0,0,0},{0,0,0,0},{0,0,0,0}}};

  // prologue: stage W half 0, load x group 0
  stageW(0);
  float xc0[4], xc1[4], xn0[4], xn1[4];
#pragma unroll
  for (int s2 = 0; s2 < 4; ++s2) {
    xc0[s2] = xq[4 * s2];
    xc1[s2] = xq[16 * I_SZ + 4 * s2];
  }
  __syncthreads();   // scl + W half 0 visible

#pragma unroll 1
  for (int h = 0; h < 2; ++h) {
#pragma unroll 1
    for (int g = 0; g < 8; ++g) {
      // prefetch x for next group (last group of h=1 has no successor)
      const int gn = h * 8 + g + 1;
      if (gn < 16) {
        const int off = gn * 16;
#pragma unroll
        for (int s2 = 0; s2 < 4; ++s2) {
          xn0[s2] = xq[off + 4 * s2];
          xn1[s2] = xq[16 * I_SZ + off + 4 * s2];
        }
      }
#pragma unroll
      for (int s2 = 0; s2 < 4; ++s2) {
        const int gs = g * 4 + s2;            // k-step within half, 0..31
        const int f = h * 128 + gs * 4 + fk;  // global feature 0..255
        const float2 s2c = scl[f];
        const bf16x8 a0 = evalOne(xc0[s2], s2c);
        const bf16x8 a1 = evalOne(xc1[s2], s2c);
        const int cp = gs * 4 + fk;           // chunk within half, 0..127
        const int grp = cp & ~7, low = cp & 7;
        bf16x8 bg[4];
#pragma unroll
        for (int n = 0; n < 4; ++n) {
          const int row = n * 16 + fr;
          const int cidx = grp | (low ^ (row & 7));
          bg[n] = *reinterpret_cast<const bf16x8*>(&Wlds[row][cidx * 8]);
        }
#pragma unroll
        for (int n = 0; n < 4; ++n) {
          acc[0][n] = __builtin_amdgcn_mfma_f32_16x16x32_bf16(a0, bg[n], acc[0][n], 0, 0, 0);
          acc[1][n] = __builtin_amdgcn_mfma_f32_16x16x32_bf16(a1, bg[n], acc[1][n], 0, 0, 0);
        }
      }
#pragma unroll
      for (int s2 = 0; s2 < 4; ++s2) { xc0[s2] = xn0[s2]; xc1[s2] = xn1[s2]; }
    }
    if (h == 0) {
      __syncthreads();   // all waves done reading W half 0
      stageW(1);
      __syncthreads();   // W half 1 visible (drains vmcnt)
    }
  }

  // epilogue: C/D layout col=lane&15, row=(lane>>4)*4+reg  [m89/m91]
#pragma unroll
  for (int m = 0; m < 2; ++m)
#pragma unroll
    for (int n = 0; n < 4; ++n) {
      const int col = c0 + n * 16 + fr;
      const float bc = bias[col];
#pragma unroll
      for (int r = 0; r < 4; ++r) {
        const int row = r0 + wave * 32 + m * 16 + fk * 4 + r;
        out[(size_t)row * O_SZ + col] = acc[m][n][r] + bc;
      }
    }
}

extern "C" void kernel_launch(void* const* d_in, const int* in_sizes, int n_in,
                              void* d_out, int out_size, void* d_ws, size_t ws_size,
                              hipStream_t stream) {
  const float* x     = (const float*)d_in[0];
  const float* bw    = (const float*)d_in[1];
  const float* sw    = (const float*)d_in[2];
  const float* coeff = (const float*)d_in[3];
  const float* bias  = (const float*)d_in[4];
  float* out = (float*)d_out;

  char* ws = (char*)d_ws;
  __hip_bfloat16* Wbuf = (__hip_bfloat16*)ws;                    // 1 MiB
  float* pmin   = (float*)(ws + (size_t)O_SZ * KDIM * 2);        // 128 KiB
  float* pmax   = pmin + NPART * I_SZ;                           // 128 KiB
  float* cenrhw = pmax + NPART * I_SZ;                           // 2 KiB

  minmax_partial<<<NPART, 256, 0, stream>>>(x, pmin, pmax);
  pack_W<<<(O_SZ * I_SZ) / 256, 256, 0, stream>>>(bw, sw, coeff, Wbuf,
                                                  pmin, pmax, cenrhw);
  gemm_fused<<<(B_SZ / BMB) * (O_SZ / BNB), 256, 0, stream>>>(x, Wbuf, cenrhw,
                                                              bias, out);
}